// Round 1
// baseline (962.543 us; speedup 1.0000x reference)
//
#include <hip/hip_runtime.h>
#include <cstdint>
#include <cstddef>

// ---------------------------------------------------------------------------
// BitMoE FFN (top-2 of 8 experts), MI355X/gfx950.
// All GEMMs run as int8 MFMA (exact integer math) + one float rescale:
//   xq ints in [-7,7], ternary weights in {-1,0,1}, hq ints in [-127,127].
// Two mandatory fp32 passes over the 402MB weights (scale, then quantize)
// dominate HBM traffic; GEMMs read the 100MB int8 copies (L3-resident).
// ---------------------------------------------------------------------------

#define T_TOK 2048
#define HDIM  1024
#define FDIM  4096
#define NEXP  8
#define FH    (FDIM * HDIM)     // 4194304 = 2^22
#define KTOP  2253              // ceil(0.55 * 4096)
#define EPSF  1e-8f

typedef int v4i  __attribute__((ext_vector_type(4)));
typedef int v16i __attribute__((ext_vector_type(16)));

// ---------------- pass 1: per-matrix mean|w| partials ----------------------
// grid (24 matrices, 64 blocks), block 256. Each block sums 65536 elems.
__global__ __launch_bounds__(256) void k_wabs_partial(const float* __restrict__ wg,
                                                      const float* __restrict__ wu,
                                                      const float* __restrict__ wd,
                                                      float* __restrict__ partials) {
  int m = blockIdx.x, blk = blockIdx.y, tid = threadIdx.x;
  const float* base = (m < 8) ? (wg + (size_t)m * FH)
                    : (m < 16) ? (wu + (size_t)(m - 8) * FH)
                               : (wd + (size_t)(m - 16) * FH);
  size_t start = (size_t)blk * 65536;
  float s = 0.f;
#pragma unroll 4
  for (int i = 0; i < 64; i++) {
    float4 v = *(const float4*)(base + start + (size_t)i * 1024 + tid * 4);
    s += fabsf(v.x) + fabsf(v.y) + fabsf(v.z) + fabsf(v.w);
  }
  for (int o = 32; o > 0; o >>= 1) s += __shfl_down(s, o);
  __shared__ float lds[4];
  if ((tid & 63) == 0) lds[tid >> 6] = s;
  __syncthreads();
  if (tid == 0) partials[m * 64 + blk] = lds[0] + lds[1] + lds[2] + lds[3];
}

// ------------- finalize scales + quantize router weights -------------------
__global__ __launch_bounds__(256) void k_scales(const float* __restrict__ wr,
                                                const float* __restrict__ partials,
                                                float* __restrict__ s_w,
                                                float* __restrict__ wrq) {
  int tid = threadIdx.x;
  __shared__ float lds[4];
  __shared__ float sbc;
  for (int m = 0; m < 24; m++) {
    float v = 0.f;
    if (tid < 64) v = partials[m * 64 + tid];
    for (int o = 32; o > 0; o >>= 1) v += __shfl_down(v, o);
    if ((tid & 63) == 0) lds[tid >> 6] = v;
    __syncthreads();
    if (tid == 0) s_w[m] = fmaxf((lds[0] + lds[1] + lds[2] + lds[3]) / (float)FH, EPSF);
    __syncthreads();
  }
  // router: per-tensor absmax int8 scale
  float mx = 0.f;
  for (int i = tid; i < NEXP * HDIM; i += 256) mx = fmaxf(mx, fabsf(wr[i]));
  for (int o = 32; o > 0; o >>= 1) mx = fmaxf(mx, __shfl_down(mx, o));
  if ((tid & 63) == 0) lds[tid >> 6] = mx;
  __syncthreads();
  if (tid == 0)
    sbc = fmaxf(fmaxf(fmaxf(lds[0], lds[1]), fmaxf(lds[2], lds[3])), EPSF) / 127.0f;
  __syncthreads();
  float s = sbc;
  for (int i = tid; i < NEXP * HDIM; i += 256) {
    float q = fminf(fmaxf(rintf(wr[i] / s), -127.f), 127.f);
    wrq[i] = q * s;
  }
}

// ---------------- pass 2: ternary-quantize weights to int8 -----------------
__global__ __launch_bounds__(256) void k_quant_w(const float* __restrict__ w,
                                                 signed char* __restrict__ q,
                                                 const float* __restrict__ scales) {
  const size_t total16 = (size_t)NEXP * FH / 16;
  for (size_t i16 = (size_t)blockIdx.x * 256 + threadIdx.x; i16 < total16;
       i16 += (size_t)gridDim.x * 256) {
    int e = (int)(i16 >> 18);           // FH/16 = 2^18 groups per expert
    float s = scales[e];
    const float4* src = (const float4*)(w + i16 * 16);
    signed char outb[16];
#pragma unroll
    for (int j = 0; j < 4; j++) {
      float4 v = src[j];
      outb[j * 4 + 0] = (signed char)(int)fminf(fmaxf(rintf(v.x / s), -1.f), 1.f);
      outb[j * 4 + 1] = (signed char)(int)fminf(fmaxf(rintf(v.y / s), -1.f), 1.f);
      outb[j * 4 + 2] = (signed char)(int)fminf(fmaxf(rintf(v.z / s), -1.f), 1.f);
      outb[j * 4 + 3] = (signed char)(int)fminf(fmaxf(rintf(v.w / s), -1.f), 1.f);
    }
    *(int4*)(q + i16 * 16) = *(const int4*)outb;
  }
}

// ------------- per-token int4 act quant + router + top-2 -------------------
__global__ __launch_bounds__(256) void k_act_router(const float* __restrict__ x,
                                                    const float* __restrict__ wrq,
                                                    signed char* __restrict__ xq,
                                                    float* __restrict__ sx,
                                                    int* __restrict__ tok_e,
                                                    float* __restrict__ tok_g,
                                                    int* __restrict__ cnt) {
  int t = blockIdx.x, tid = threadIdx.x;
  float4 xv = *(const float4*)(x + (size_t)t * HDIM + tid * 4);
  __shared__ float lds[4];
  __shared__ float sbc;
  __shared__ float part[8][256];
  __shared__ float lg[8];
  float mx = fmaxf(fmaxf(fabsf(xv.x), fabsf(xv.y)), fmaxf(fabsf(xv.z), fabsf(xv.w)));
  for (int o = 32; o > 0; o >>= 1) mx = fmaxf(mx, __shfl_down(mx, o));
  if ((tid & 63) == 0) lds[tid >> 6] = mx;
  __syncthreads();
  if (tid == 0)
    sbc = fmaxf(fmaxf(fmaxf(lds[0], lds[1]), fmaxf(lds[2], lds[3])), EPSF) / 7.0f;
  __syncthreads();
  float s = sbc;
  int q0 = (int)fminf(fmaxf(rintf(xv.x / s), -7.f), 7.f);
  int q1 = (int)fminf(fmaxf(rintf(xv.y / s), -7.f), 7.f);
  int q2 = (int)fminf(fmaxf(rintf(xv.z / s), -7.f), 7.f);
  int q3 = (int)fminf(fmaxf(rintf(xv.w / s), -7.f), 7.f);
  int packed = (q0 & 255) | ((q1 & 255) << 8) | ((q2 & 255) << 16) | (q3 << 24);
  *(int*)(xq + (size_t)t * HDIM + tid * 4) = packed;
  if (tid == 0) sx[t] = s;
  // router logits on UNquantized x
#pragma unroll
  for (int e = 0; e < 8; e++) {
    float4 w = *(const float4*)(wrq + e * HDIM + tid * 4);
    part[e][tid] = xv.x * w.x + xv.y * w.y + xv.z * w.z + xv.w * w.w;
  }
  __syncthreads();
  if (tid < 8) {
    float sum = 0.f;
    for (int i = 0; i < 256; i++) sum += part[tid][i];
    lg[tid] = sum;
  }
  __syncthreads();
  if (tid == 0) {
    float m = lg[0];
    for (int e = 1; e < 8; e++) m = fmaxf(m, lg[e]);
    float p[8]; float S = 0.f;
    for (int e = 0; e < 8; e++) { p[e] = expf(lg[e] - m); S += p[e]; }
    for (int e = 0; e < 8; e++) p[e] /= S;
    int e0 = 0;
    for (int e = 1; e < 8; e++) if (p[e] > p[e0]) e0 = e;          // ties: lowest idx
    int e1 = -1;
    for (int e = 0; e < 8; e++) { if (e == e0) continue; if (e1 < 0 || p[e] > p[e1]) e1 = e; }
    float g0 = p[e0], g1 = p[e1], gs = g0 + g1;
    tok_e[2 * t] = e0;  tok_e[2 * t + 1] = e1;
    tok_g[2 * t] = g0 / gs;  tok_g[2 * t + 1] = g1 / gs;
    atomicAdd(&cnt[e0], 1); atomicAdd(&cnt[e1], 1);
  }
}

// -------------------- expert offsets + tile plan ---------------------------
__global__ void k_plan(const int* __restrict__ cnt, int* __restrict__ offs,
                       int* __restrict__ tile_e, int* __restrict__ tile_m0,
                       int* __restrict__ tile_cnt) {
  if (threadIdx.x == 0 && blockIdx.x == 0) {
    int o = 0;
    for (int e = 0; e < 8; e++) { offs[e] = o; o += cnt[e]; }
    offs[8] = o;
    int tt = 0;
    for (int e = 0; e < 8; e++)
      for (int m0 = 0; m0 < cnt[e]; m0 += 64) { tile_e[tt] = e; tile_m0[tt] = m0; tt++; }
    *tile_cnt = tt;
  }
}

__global__ __launch_bounds__(256) void k_scatter(const int* __restrict__ tok_e,
                                                 const float* __restrict__ tok_g,
                                                 const float* __restrict__ sx,
                                                 const int* __restrict__ offs,
                                                 int* __restrict__ cnt2,
                                                 int* __restrict__ pair_tok,
                                                 float* __restrict__ pair_gate,
                                                 float* __restrict__ pair_sx) {
  int t = blockIdx.x * 256 + threadIdx.x;
  if (t >= T_TOK) return;
  for (int k = 0; k < 2; k++) {
    int e = tok_e[2 * t + k];
    int pos = offs[e] + atomicAdd(&cnt2[e], 1);
    pair_tok[pos] = t;
    pair_gate[pos] = tok_g[2 * t + k];
    pair_sx[pos] = sx[t];
  }
}

// -------- gate/up int8 MFMA GEMM + fused SiLU*u, writes h (fp32) -----------
// block: 256 thr (4 waves). tile: M=64 pairs x N=128 f-cols, K=H=1024.
// Wave w owns n-subtile w*32; operands loaded straight from global (L1/L2).
__global__ __launch_bounds__(256) void k_gemm_gu(const signed char* __restrict__ xq,
                                                 const signed char* __restrict__ wgq,
                                                 const signed char* __restrict__ wuq,
                                                 const int* __restrict__ tile_e,
                                                 const int* __restrict__ tile_m0,
                                                 const int* __restrict__ tile_cnt,
                                                 const int* __restrict__ cnt,
                                                 const int* __restrict__ offs,
                                                 const int* __restrict__ pair_tok,
                                                 const float* __restrict__ pair_sx,
                                                 const float* __restrict__ s_w,
                                                 float* __restrict__ hbuf) {
  int bx = blockIdx.x;
  if (bx >= *tile_cnt) return;
  int e = tile_e[bx], m0 = tile_m0[bx];
  int cnt_e = cnt[e], pbase = offs[e];
  int tid = threadIdx.x;
  int wave = tid >> 6, lane = tid & 63, ln = lane & 31, kh = lane >> 5;
  int r0 = m0 + ln, r1 = m0 + 32 + ln;
  int tok0 = pair_tok[pbase + ((r0 < cnt_e) ? r0 : cnt_e - 1)];
  int tok1 = pair_tok[pbase + ((r1 < cnt_e) ? r1 : cnt_e - 1)];
  const signed char* ap0 = xq + (size_t)tok0 * HDIM + kh * 16;
  const signed char* ap1 = xq + (size_t)tok1 * HDIM + kh * 16;
  int fbase = blockIdx.y * 128 + wave * 32;
  const signed char* bg = wgq + (size_t)e * FH + (size_t)(fbase + ln) * HDIM + kh * 16;
  const signed char* bu = wuq + (size_t)e * FH + (size_t)(fbase + ln) * HDIM + kh * 16;
  v16i accg0 = {0}, accg1 = {0}, accu0 = {0}, accu1 = {0};
#pragma unroll 4
  for (int k0 = 0; k0 < HDIM; k0 += 32) {
    v4i a0 = *(const v4i*)(ap0 + k0);
    v4i a1 = *(const v4i*)(ap1 + k0);
    v4i b0 = *(const v4i*)(bg + k0);
    v4i b1 = *(const v4i*)(bu + k0);
    accg0 = __builtin_amdgcn_mfma_i32_32x32x32_i8(a0, b0, accg0, 0, 0, 0);
    accg1 = __builtin_amdgcn_mfma_i32_32x32x32_i8(a1, b0, accg1, 0, 0, 0);
    accu0 = __builtin_amdgcn_mfma_i32_32x32x32_i8(a0, b1, accu0, 0, 0, 0);
    accu1 = __builtin_amdgcn_mfma_i32_32x32x32_i8(a1, b1, accu1, 0, 0, 0);
  }
  float sg = s_w[e], su = s_w[8 + e];
#pragma unroll
  for (int r = 0; r < 16; r++) {
    int rr = (r & 3) + 8 * (r >> 2) + 4 * kh;   // C/D row map, 32x32 shape
#pragma unroll
    for (int mt = 0; mt < 2; mt++) {
      int ml = m0 + mt * 32 + rr;
      if (ml < cnt_e) {
        int p = pbase + ml;
        float sxv = pair_sx[p];
        int gi = (mt == 0) ? accg0[r] : accg1[r];
        int ui = (mt == 0) ? accu0[r] : accu1[r];
        float gf = (float)gi * (sxv * sg);
        float uf = (float)ui * (sxv * su);
        float h = gf / (1.0f + expf(-gf)) * uf;   // silu(g)*u
        hbuf[(size_t)p * FDIM + fbase + ln] = h;
      }
    }
  }
}

// ------- per-pair exact top-k radix select + int8 quant of h ---------------
__global__ __launch_bounds__(256) void k_select(const float* __restrict__ hbuf,
                                                signed char* __restrict__ hq,
                                                const float* __restrict__ pair_gate,
                                                float* __restrict__ pair_f) {
  int p = blockIdx.x, tid = threadIdx.x;
  const float* row = hbuf + (size_t)p * FDIM;
  float vals[16];
  unsigned int ua[16];
  float mx = 0.f;
#pragma unroll
  for (int j = 0; j < 16; j++) {
    float v = row[tid + j * 256];
    vals[j] = v;
    unsigned int u = __float_as_uint(v) & 0x7fffffffu;
    ua[j] = u;
    mx = fmaxf(mx, __uint_as_float(u));
  }
  __shared__ float lds[4];
  __shared__ float smax;
  __shared__ unsigned int hist[256];
  __shared__ unsigned int S[256];
  __shared__ unsigned int prefix_s;
  __shared__ int need_s;
  for (int o = 32; o > 0; o >>= 1) mx = fmaxf(mx, __shfl_down(mx, o));
  if ((tid & 63) == 0) lds[tid >> 6] = mx;
  __syncthreads();
  if (tid == 0) {
    smax = fmaxf(fmaxf(lds[0], lds[1]), fmaxf(lds[2], lds[3]));
    prefix_s = 0u;
    need_s = KTOP;
  }
  __syncthreads();
  for (int pass = 3; pass >= 0; pass--) {
    hist[tid] = 0u;
    __syncthreads();
    unsigned int pref = prefix_s;
    int shift = pass * 8;
#pragma unroll
    for (int j = 0; j < 16; j++) {
      unsigned int u = ua[j];
      bool in = (pass == 3) || ((u >> (shift + 8)) == (pref >> (shift + 8)));
      if (in) atomicAdd(&hist[(u >> shift) & 255], 1u);
    }
    __syncthreads();
    S[tid] = hist[tid];
    __syncthreads();
    for (int off = 1; off < 256; off <<= 1) {
      unsigned int v = (tid + off < 256) ? S[tid + off] : 0u;
      __syncthreads();
      S[tid] += v;
      __syncthreads();
    }
    int need = need_s;
    unsigned int above = (tid < 255) ? S[tid + 1] : 0u;
    if ((int)S[tid] >= need && (int)above < need) {
      need_s = need - (int)above;
      prefix_s = prefix_s | ((unsigned int)tid << shift);
    }
    __syncthreads();
  }
  unsigned int thr_bits = prefix_s;              // exact k-th largest |h|
  float sq = fmaxf(smax, EPSF) / 127.0f;         // max|xm| == max|h|
#pragma unroll
  for (int j = 0; j < 16; j++) {
    float m = (ua[j] >= thr_bits) ? vals[j] : 0.0f;
    float q = fminf(fmaxf(rintf(m / sq), -127.f), 127.f);
    hq[(size_t)p * FDIM + tid + j * 256] = (signed char)(int)q;
  }
  if (tid == 0) pair_f[p] = pair_gate[p] * sq;
}

// ---------- down int8 MFMA GEMM + gated atomic combine into out ------------
__global__ __launch_bounds__(256) void k_gemm_down(const signed char* __restrict__ hq,
                                                   const signed char* __restrict__ wdq,
                                                   const int* __restrict__ tile_e,
                                                   const int* __restrict__ tile_m0,
                                                   const int* __restrict__ tile_cnt,
                                                   const int* __restrict__ cnt,
                                                   const int* __restrict__ offs,
                                                   const int* __restrict__ pair_tok,
                                                   const float* __restrict__ pair_f,
                                                   const float* __restrict__ s_w,
                                                   float* __restrict__ out) {
  int bx = blockIdx.x;
  if (bx >= *tile_cnt) return;
  int e = tile_e[bx], m0 = tile_m0[bx];
  int cnt_e = cnt[e], pbase = offs[e];
  int tid = threadIdx.x;
  int wave = tid >> 6, lane = tid & 63, ln = lane & 31, kh = lane >> 5;
  int r0 = m0 + ln, r1 = m0 + 32 + ln;
  int p0 = pbase + ((r0 < cnt_e) ? r0 : cnt_e - 1);
  int p1 = pbase + ((r1 < cnt_e) ? r1 : cnt_e - 1);
  const signed char* ap0 = hq + (size_t)p0 * FDIM + kh * 16;
  const signed char* ap1 = hq + (size_t)p1 * FDIM + kh * 16;
  int nbase = blockIdx.y * 128 + wave * 32;
  const signed char* bp = wdq + (size_t)e * FH + (size_t)(nbase + ln) * FDIM + kh * 16;
  v16i acc0 = {0}, acc1 = {0};
#pragma unroll 4
  for (int k0 = 0; k0 < FDIM; k0 += 32) {
    v4i a0 = *(const v4i*)(ap0 + k0);
    v4i a1 = *(const v4i*)(ap1 + k0);
    v4i b = *(const v4i*)(bp + k0);
    acc0 = __builtin_amdgcn_mfma_i32_32x32x32_i8(a0, b, acc0, 0, 0, 0);
    acc1 = __builtin_amdgcn_mfma_i32_32x32x32_i8(a1, b, acc1, 0, 0, 0);
  }
  float sd = s_w[16 + e];
  int col = nbase + ln;
#pragma unroll
  for (int r = 0; r < 16; r++) {
    int rr = (r & 3) + 8 * (r >> 2) + 4 * kh;
#pragma unroll
    for (int mt = 0; mt < 2; mt++) {
      int ml = m0 + mt * 32 + rr;
      if (ml < cnt_e) {
        int p = pbase + ml;
        int ai = (mt == 0) ? acc0[r] : acc1[r];
        float v = (float)ai * (pair_f[p] * sd);
        atomicAdd(out + (size_t)pair_tok[p] * HDIM + col, v);
      }
    }
  }
}

// ---------------------------------------------------------------------------
extern "C" void kernel_launch(void* const* d_in, const int* in_sizes, int n_in,
                              void* d_out, int out_size, void* d_ws, size_t ws_size,
                              hipStream_t stream) {
  const float* x  = (const float*)d_in[0];
  const float* wg = (const float*)d_in[1];
  const float* wu = (const float*)d_in[2];
  const float* wd = (const float*)d_in[3];
  const float* wr = (const float*)d_in[4];
  float* out = (float*)d_out;
  char* ws = (char*)d_ws;
  (void)in_sizes; (void)n_in; (void)out_size; (void)ws_size;

  size_t o = 0;
  auto alloc = [&](size_t b) { size_t r = o; o += (b + 255) & ~(size_t)255; return r; };
  float* partials   = (float*)(ws + alloc(24 * 64 * 4));
  float* s_w        = (float*)(ws + alloc(24 * 4));
  float* wrq        = (float*)(ws + alloc((size_t)NEXP * HDIM * 4));
  int*   tok_e      = (int*)  (ws + alloc((size_t)T_TOK * 2 * 4));
  float* tok_g      = (float*)(ws + alloc((size_t)T_TOK * 2 * 4));
  int*   cnt        = (int*)  (ws + alloc(256));      // cnt[8] then cnt2[8]
  int*   cnt2       = cnt + 8;
  int*   offs       = (int*)  (ws + alloc(16 * 4));
  int*   tile_e     = (int*)  (ws + alloc(128 * 4));
  int*   tile_m0    = (int*)  (ws + alloc(128 * 4));
  int*   tile_cnt   = (int*)  (ws + alloc(4));
  int*   pair_tok   = (int*)  (ws + alloc(4096 * 4));
  float* pair_gate  = (float*)(ws + alloc(4096 * 4));
  float* pair_sx    = (float*)(ws + alloc(4096 * 4));
  float* pair_f     = (float*)(ws + alloc(4096 * 4));
  float* sx         = (float*)(ws + alloc((size_t)T_TOK * 4));
  signed char* xq   = (signed char*)(ws + alloc((size_t)T_TOK * HDIM));
  signed char* wgq  = (signed char*)(ws + alloc((size_t)NEXP * FH));
  signed char* wuq  = (signed char*)(ws + alloc((size_t)NEXP * FH));
  signed char* wdq  = (signed char*)(ws + alloc((size_t)NEXP * FH));
  float* hbuf       = (float*)(ws + alloc((size_t)4096 * FDIM * 4));
  signed char* hq   = (signed char*)(ws + alloc((size_t)4096 * FDIM));

  hipMemsetAsync(cnt, 0, 64, stream);
  hipMemsetAsync(out, 0, (size_t)T_TOK * HDIM * 4, stream);

  k_wabs_partial<<<dim3(24, 64), 256, 0, stream>>>(wg, wu, wd, partials);
  k_scales<<<1, 256, 0, stream>>>(wr, partials, s_w, wrq);
  k_quant_w<<<4096, 256, 0, stream>>>(wg, wgq, s_w);
  k_quant_w<<<4096, 256, 0, stream>>>(wu, wuq, s_w + 8);
  k_quant_w<<<4096, 256, 0, stream>>>(wd, wdq, s_w + 16);
  k_act_router<<<T_TOK, 256, 0, stream>>>(x, wrq, xq, sx, tok_e, tok_g, cnt);
  k_plan<<<1, 64, 0, stream>>>(cnt, offs, tile_e, tile_m0, tile_cnt);
  k_scatter<<<8, 256, 0, stream>>>(tok_e, tok_g, sx, offs, cnt2, pair_tok, pair_gate, pair_sx);
  k_gemm_gu<<<dim3(72, 32), 256, 0, stream>>>(xq, wgq, wuq, tile_e, tile_m0, tile_cnt,
                                              cnt, offs, pair_tok, pair_sx, s_w, hbuf);
  k_select<<<4096, 256, 0, stream>>>(hbuf, hq, pair_gate, pair_f);
  k_gemm_down<<<dim3(72, 8), 256, 0, stream>>>(hq, wdq, tile_e, tile_m0, tile_cnt,
                                               cnt, offs, pair_tok, pair_f, s_w, out);
}

// Round 2
// 816.559 us; speedup vs baseline: 1.1788x; 1.1788x over previous
//
#include <hip/hip_runtime.h>
#include <cstdint>
#include <cstddef>

// ---------------------------------------------------------------------------
// BitMoE FFN (top-2 of 8 experts), MI355X/gfx950.  Round 2.
// All GEMM operands (int8) are pre-packed in MFMA fragment order:
//   P[grp][chunk c][lane][16B],  lane l -> row grp*32+(l&31), k = c*32+(l>>5)*16
// so every GEMM global load is a fully-coalesced 1KB wave transaction.
// Top-k threshold via exact 31-step bisection on |h| bits (ballot+popcount).
// ---------------------------------------------------------------------------

#define T_TOK 2048
#define HDIM  1024
#define FDIM  4096
#define NEXP  8
#define FH    (FDIM * HDIM)     // 2^22
#define KTOP  2253              // ceil(0.55 * 4096)
#define EPSF  1e-8f
#define PPAD  4608              // 4096 pairs + per-expert 64-alignment padding

typedef int v4i  __attribute__((ext_vector_type(4)));
typedef int v16i __attribute__((ext_vector_type(16)));

// ---------------- pass 1: per-matrix mean|w| partials ----------------------
__global__ __launch_bounds__(256) void k_wabs_partial(const float* __restrict__ wg,
                                                      const float* __restrict__ wu,
                                                      const float* __restrict__ wd,
                                                      float* __restrict__ partials) {
  int m = blockIdx.x, blk = blockIdx.y, tid = threadIdx.x;
  const float* base = (m < 8) ? (wg + (size_t)m * FH)
                    : (m < 16) ? (wu + (size_t)(m - 8) * FH)
                               : (wd + (size_t)(m - 16) * FH);
  size_t start = (size_t)blk * 65536;
  float s = 0.f;
#pragma unroll 4
  for (int i = 0; i < 64; i++) {
    float4 v = *(const float4*)(base + start + (size_t)i * 1024 + tid * 4);
    s += fabsf(v.x) + fabsf(v.y) + fabsf(v.z) + fabsf(v.w);
  }
  for (int o = 32; o > 0; o >>= 1) s += __shfl_down(s, o);
  __shared__ float lds[4];
  if ((tid & 63) == 0) lds[tid >> 6] = s;
  __syncthreads();
  if (tid == 0) partials[m * 64 + blk] = lds[0] + lds[1] + lds[2] + lds[3];
}

// ------------- finalize scales + quantize router weights -------------------
__global__ __launch_bounds__(256) void k_scales(const float* __restrict__ wr,
                                                const float* __restrict__ partials,
                                                float* __restrict__ s_w,
                                                float* __restrict__ wrq) {
  int tid = threadIdx.x;
  __shared__ float lds[4];
  __shared__ float sbc;
  for (int m = 0; m < 24; m++) {
    float v = 0.f;
    if (tid < 64) v = partials[m * 64 + tid];
    for (int o = 32; o > 0; o >>= 1) v += __shfl_down(v, o);
    if ((tid & 63) == 0) lds[tid >> 6] = v;
    __syncthreads();
    if (tid == 0) s_w[m] = fmaxf((lds[0] + lds[1] + lds[2] + lds[3]) / (float)FH, EPSF);
    __syncthreads();
  }
  float mx = 0.f;
  for (int i = tid; i < NEXP * HDIM; i += 256) mx = fmaxf(mx, fabsf(wr[i]));
  for (int o = 32; o > 0; o >>= 1) mx = fmaxf(mx, __shfl_down(mx, o));
  if ((tid & 63) == 0) lds[tid >> 6] = mx;
  __syncthreads();
  if (tid == 0)
    sbc = fmaxf(fmaxf(fmaxf(lds[0], lds[1]), fmaxf(lds[2], lds[3])), EPSF) / 127.0f;
  __syncthreads();
  float s = sbc;
  for (int i = tid; i < NEXP * HDIM; i += 256) {
    float q = fminf(fmaxf(rintf(wr[i] / s), -127.f), 127.f);
    wrq[i] = q * s;
  }
}

// ------- pass 2: ternary-quantize weights, writing MFMA-fragment pack ------
// Layout: [e][grp=row/32][c=k/32][lane=0..63][16B]; lane l covers
// row grp*32+(l&31), k = c*32+(l>>5)*16 .. +16.  One 16B chunk per thread.
template <int KD, int RD>
__global__ __launch_bounds__(256) void k_quant_pack(const float* __restrict__ w,
                                                    signed char* __restrict__ q,
                                                    const float* __restrict__ scales) {
  constexpr int CCH = KD / 32, GR = RD / 32;
  int idx = blockIdx.x * 256 + threadIdx.x;          // < 2^21
  int l = idx & 63;
  int c = (idx >> 6) % CCH;
  int g = (idx / (64 * CCH)) % GR;
  int e = idx / (64 * CCH * GR);
  const float* src = w + ((size_t)e * RD + g * 32 + (l & 31)) * KD + c * 32 + (l >> 5) * 16;
  float s = scales[e];
  signed char outb[16];
#pragma unroll
  for (int j = 0; j < 4; j++) {
    float4 v = *(const float4*)(src + j * 4);
    outb[j * 4 + 0] = (signed char)(int)fminf(fmaxf(rintf(v.x / s), -1.f), 1.f);
    outb[j * 4 + 1] = (signed char)(int)fminf(fmaxf(rintf(v.y / s), -1.f), 1.f);
    outb[j * 4 + 2] = (signed char)(int)fminf(fmaxf(rintf(v.z / s), -1.f), 1.f);
    outb[j * 4 + 3] = (signed char)(int)fminf(fmaxf(rintf(v.w / s), -1.f), 1.f);
  }
  *(int4*)(q + (size_t)idx * 16) = *(const int4*)outb;
}

// ------------- per-token int4 act quant + router + top-2 -------------------
__global__ __launch_bounds__(256) void k_act_router(const float* __restrict__ x,
                                                    const float* __restrict__ wrq,
                                                    signed char* __restrict__ xq,
                                                    float* __restrict__ sx,
                                                    int* __restrict__ tok_e,
                                                    float* __restrict__ tok_g,
                                                    int* __restrict__ cnt) {
  int t = blockIdx.x, tid = threadIdx.x;
  float4 xv = *(const float4*)(x + (size_t)t * HDIM + tid * 4);
  __shared__ float lds[4];
  __shared__ float sbc;
  __shared__ float part[8][256];
  __shared__ float lg[8];
  float mx = fmaxf(fmaxf(fabsf(xv.x), fabsf(xv.y)), fmaxf(fabsf(xv.z), fabsf(xv.w)));
  for (int o = 32; o > 0; o >>= 1) mx = fmaxf(mx, __shfl_down(mx, o));
  if ((tid & 63) == 0) lds[tid >> 6] = mx;
  __syncthreads();
  if (tid == 0)
    sbc = fmaxf(fmaxf(fmaxf(lds[0], lds[1]), fmaxf(lds[2], lds[3])), EPSF) / 7.0f;
  __syncthreads();
  float s = sbc;
  int q0 = (int)fminf(fmaxf(rintf(xv.x / s), -7.f), 7.f);
  int q1 = (int)fminf(fmaxf(rintf(xv.y / s), -7.f), 7.f);
  int q2 = (int)fminf(fmaxf(rintf(xv.z / s), -7.f), 7.f);
  int q3 = (int)fminf(fmaxf(rintf(xv.w / s), -7.f), 7.f);
  int packed = (q0 & 255) | ((q1 & 255) << 8) | ((q2 & 255) << 16) | (q3 << 24);
  *(int*)(xq + (size_t)t * HDIM + tid * 4) = packed;
  if (tid == 0) sx[t] = s;
#pragma unroll
  for (int e = 0; e < 8; e++) {
    float4 w = *(const float4*)(wrq + e * HDIM + tid * 4);
    part[e][tid] = xv.x * w.x + xv.y * w.y + xv.z * w.z + xv.w * w.w;
  }
  __syncthreads();
  if (tid < 8) {
    float sum = 0.f;
    for (int i = 0; i < 256; i++) sum += part[tid][i];
    lg[tid] = sum;
  }
  __syncthreads();
  if (tid == 0) {
    float m = lg[0];
    for (int e = 1; e < 8; e++) m = fmaxf(m, lg[e]);
    float p[8]; float S = 0.f;
    for (int e = 0; e < 8; e++) { p[e] = expf(lg[e] - m); S += p[e]; }
    for (int e = 0; e < 8; e++) p[e] /= S;
    int e0 = 0;
    for (int e = 1; e < 8; e++) if (p[e] > p[e0]) e0 = e;
    int e1 = -1;
    for (int e = 0; e < 8; e++) { if (e == e0) continue; if (e1 < 0 || p[e] > p[e1]) e1 = e; }
    float g0 = p[e0], g1 = p[e1], gs = g0 + g1;
    tok_e[2 * t] = e0;  tok_e[2 * t + 1] = e1;
    tok_g[2 * t] = g0 / gs;  tok_g[2 * t + 1] = g1 / gs;
    atomicAdd(&cnt[e0], 1); atomicAdd(&cnt[e1], 1);
  }
}

// ------------ expert offsets (64-aligned!) + tile plan ---------------------
__global__ void k_plan(const int* __restrict__ cnt, int* __restrict__ offs,
                       int* __restrict__ tile_e, int* __restrict__ tile_m0,
                       int* __restrict__ tile_cnt) {
  if (threadIdx.x == 0 && blockIdx.x == 0) {
    int o = 0;
    for (int e = 0; e < 8; e++) { offs[e] = o; o += (cnt[e] + 63) & ~63; }
    offs[8] = o;
    int tt = 0;
    for (int e = 0; e < 8; e++)
      for (int m0 = 0; m0 < cnt[e]; m0 += 64) { tile_e[tt] = e; tile_m0[tt] = m0; tt++; }
    *tile_cnt = tt;
  }
}

__global__ __launch_bounds__(256) void k_scatter(const int* __restrict__ tok_e,
                                                 const float* __restrict__ tok_g,
                                                 const float* __restrict__ sx,
                                                 const int* __restrict__ offs,
                                                 int* __restrict__ cnt2,
                                                 int* __restrict__ pair_tok,
                                                 float* __restrict__ pair_gate,
                                                 float* __restrict__ pair_sx) {
  int t = blockIdx.x * 256 + threadIdx.x;
  if (t >= T_TOK) return;
  for (int k = 0; k < 2; k++) {
    int e = tok_e[2 * t + k];
    int pos = offs[e] + atomicAdd(&cnt2[e], 1);
    pair_tok[pos] = t;
    pair_gate[pos] = tok_g[2 * t + k];
    pair_sx[pos] = sx[t];
  }
}

// ----------- gather xq rows into A-fragment pack (per pair) ----------------
__global__ __launch_bounds__(256) void k_packA(const int* __restrict__ pair_tok,
                                               const signed char* __restrict__ xq,
                                               signed char* __restrict__ xqp) {
  int idx = blockIdx.x * 256 + threadIdx.x;          // < PPAD*64 = 294912
  int l = idx & 63, c = (idx >> 6) & 31, pgrp = idx >> 11;
  int p = pgrp * 32 + (l & 31);
  int tok = pair_tok[p];                             // pads memset to 0 -> safe
  const signed char* src = xq + (size_t)tok * HDIM + c * 32 + (l >> 5) * 16;
  *(int4*)(xqp + (size_t)idx * 16) = *(const int4*)src;
}

// -------- gate/up int8 MFMA GEMM + fused SiLU*u, writes h (fp16) -----------
// 256 thr / 4 waves; tile M=64 pairs x N=128 f-cols; all operands streamed
// coalesced from fragment-packed buffers (no LDS).
__global__ __launch_bounds__(256) void k_gemm_gu(const signed char* __restrict__ xqp,
                                                 const signed char* __restrict__ wgp,
                                                 const signed char* __restrict__ wup,
                                                 const int* __restrict__ tile_e,
                                                 const int* __restrict__ tile_m0,
                                                 const int* __restrict__ tile_cnt,
                                                 const int* __restrict__ cnt,
                                                 const int* __restrict__ offs,
                                                 const float* __restrict__ pair_sx,
                                                 const float* __restrict__ s_w,
                                                 unsigned short* __restrict__ hbuf) {
  int bx = blockIdx.x;
  if (bx >= *tile_cnt) return;
  int e = tile_e[bx], m0 = tile_m0[bx];
  int cnt_e = cnt[e], pbase = offs[e];
  int tid = threadIdx.x;
  int wave = tid >> 6, lane = tid & 63, ln = lane & 31, kh = lane >> 5;
  int fgrp = blockIdx.y * 4 + wave;
  const signed char* bg = wgp + (((size_t)e * 128 + fgrp) * 32) * 1024 + lane * 16;
  const signed char* bu = wup + (((size_t)e * 128 + fgrp) * 32) * 1024 + lane * 16;
  const signed char* ap = xqp + ((size_t)((pbase + m0) >> 5) * 32) * 1024 + lane * 16;
  v16i accg0 = {0}, accg1 = {0}, accu0 = {0}, accu1 = {0};
#pragma unroll 8
  for (int c = 0; c < 32; c++) {
    v4i a0 = *(const v4i*)(ap + c * 1024);
    v4i a1 = *(const v4i*)(ap + 32768 + c * 1024);
    v4i b0 = *(const v4i*)(bg + c * 1024);
    v4i b1 = *(const v4i*)(bu + c * 1024);
    accg0 = __builtin_amdgcn_mfma_i32_32x32x32_i8(a0, b0, accg0, 0, 0, 0);
    accg1 = __builtin_amdgcn_mfma_i32_32x32x32_i8(a1, b0, accg1, 0, 0, 0);
    accu0 = __builtin_amdgcn_mfma_i32_32x32x32_i8(a0, b1, accu0, 0, 0, 0);
    accu1 = __builtin_amdgcn_mfma_i32_32x32x32_i8(a1, b1, accu1, 0, 0, 0);
  }
  float sg = s_w[e], su = s_w[8 + e];
  int col = blockIdx.y * 128 + wave * 32 + ln;
#pragma unroll
  for (int r = 0; r < 16; r++) {
    int rr = (r & 3) + 8 * (r >> 2) + 4 * kh;
#pragma unroll
    for (int mt = 0; mt < 2; mt++) {
      int ml = m0 + mt * 32 + rr;
      if (ml < cnt_e) {
        int p = pbase + ml;
        float sxv = pair_sx[p];
        int gi = (mt == 0) ? accg0[r] : accg1[r];
        int ui = (mt == 0) ? accu0[r] : accu1[r];
        float gf = (float)gi * (sxv * sg);
        float uf = (float)ui * (sxv * su);
        float h = gf / (1.0f + expf(-gf)) * uf;
        ((_Float16*)hbuf)[(size_t)p * FDIM + col] = (_Float16)h;
      }
    }
  }
}

// ------- per-pair exact top-k threshold via bit-space bisection ------------
// One wave per row: lane l holds k = l*64..l*64+63. No LDS, no atomics;
// count(|h| >= mid) via ballot+popcount, 31 iterations -> exact kth bits.
// Writes hq in A-fragment pack layout for the down GEMM.
__global__ __launch_bounds__(256) void k_select(const unsigned short* __restrict__ hbuf,
                                                signed char* __restrict__ hqp,
                                                const float* __restrict__ pair_gate,
                                                float* __restrict__ pair_f) {
  int wv = threadIdx.x >> 6, lane = threadIdx.x & 63;
  int p = blockIdx.x * 4 + wv;
  const unsigned short* row = hbuf + (size_t)p * FDIM + lane * 64;
  unsigned short hs[64];
#pragma unroll
  for (int i = 0; i < 8; i++)
    *(uint4*)(hs + i * 8) = *(const uint4*)(row + i * 8);
  unsigned int ua[64];
  unsigned int mxb = 0;
#pragma unroll
  for (int j = 0; j < 64; j++) {
    float v = (float)(((const _Float16*)hs)[j]);
    unsigned int u = __float_as_uint(v) & 0x7fffffffu;
    ua[j] = u;
    mxb = (u > mxb) ? u : mxb;
  }
  for (int o = 32; o > 0; o >>= 1) {
    unsigned int t = (unsigned int)__shfl_down((int)mxb, o);
    mxb = (t > mxb) ? t : mxb;
  }
  mxb = (unsigned int)__shfl((int)mxb, 0);
  unsigned int lo = 0, hi = 0x80000000u;
  for (int it = 0; it < 31; ++it) {
    unsigned int mid = (lo + hi) >> 1;
    int cnt = 0;
#pragma unroll
    for (int j = 0; j < 64; j++)
      cnt += (int)__popcll(__ballot(ua[j] >= mid));
    if (cnt >= KTOP) lo = mid; else hi = mid;
  }
  unsigned int thr = lo;
  float smax = fmaxf(__uint_as_float(mxb), EPSF);
  float sq = smax / 127.0f;
  int pgrp = p >> 5, ln = p & 31;
#pragma unroll
  for (int gj = 0; gj < 4; gj++) {
    int c = 2 * lane + (gj >> 1);
    int kh = gj & 1;
    signed char outb[16];
#pragma unroll
    for (int t = 0; t < 16; t++) {
      int j = gj * 16 + t;
      float v = (float)(((const _Float16*)hs)[j]);
      float m = (ua[j] >= thr) ? v : 0.0f;
      float q = fminf(fmaxf(rintf(m / sq), -127.f), 127.f);
      outb[t] = (signed char)(int)q;
    }
    *(int4*)(hqp + ((size_t)((size_t)pgrp * 128 + c) * 64 + kh * 32 + ln) * 16) =
        *(const int4*)outb;
  }
  if (lane == 0) pair_f[p] = pair_gate[p] * sq;
}

// ---------- down int8 MFMA GEMM + gated atomic combine into out ------------
__global__ __launch_bounds__(256) void k_gemm_down(const signed char* __restrict__ hqp,
                                                   const signed char* __restrict__ wdp,
                                                   const int* __restrict__ tile_e,
                                                   const int* __restrict__ tile_m0,
                                                   const int* __restrict__ tile_cnt,
                                                   const int* __restrict__ cnt,
                                                   const int* __restrict__ offs,
                                                   const int* __restrict__ pair_tok,
                                                   const float* __restrict__ pair_f,
                                                   const float* __restrict__ s_w,
                                                   float* __restrict__ out) {
  int bx = blockIdx.x;
  if (bx >= *tile_cnt) return;
  int e = tile_e[bx], m0 = tile_m0[bx];
  int cnt_e = cnt[e], pbase = offs[e];
  int tid = threadIdx.x;
  int wave = tid >> 6, lane = tid & 63, ln = lane & 31, kh = lane >> 5;
  int grp_n = blockIdx.y * 4 + wave;                  // 0..31
  const signed char* bp = wdp + (((size_t)e * 32 + grp_n) * 128) * 1024 + lane * 16;
  const signed char* ap = hqp + ((size_t)((pbase + m0) >> 5) * 128) * 1024 + lane * 16;
  v16i acc0 = {0}, acc1 = {0};
#pragma unroll 8
  for (int c = 0; c < 128; c++) {
    v4i a0 = *(const v4i*)(ap + (size_t)c * 1024);
    v4i a1 = *(const v4i*)(ap + 131072 + (size_t)c * 1024);
    v4i b  = *(const v4i*)(bp + (size_t)c * 1024);
    acc0 = __builtin_amdgcn_mfma_i32_32x32x32_i8(a0, b, acc0, 0, 0, 0);
    acc1 = __builtin_amdgcn_mfma_i32_32x32x32_i8(a1, b, acc1, 0, 0, 0);
  }
  float sd = s_w[16 + e];
  int col = blockIdx.y * 128 + wave * 32 + ln;
#pragma unroll
  for (int r = 0; r < 16; r++) {
    int rr = (r & 3) + 8 * (r >> 2) + 4 * kh;
#pragma unroll
    for (int mt = 0; mt < 2; mt++) {
      int ml = m0 + mt * 32 + rr;
      if (ml < cnt_e) {
        int p = pbase + ml;
        int ai = (mt == 0) ? acc0[r] : acc1[r];
        float v = (float)ai * (pair_f[p] * sd);
        atomicAdd(out + (size_t)pair_tok[p] * HDIM + col, v);
      }
    }
  }
}

// ---------------------------------------------------------------------------
extern "C" void kernel_launch(void* const* d_in, const int* in_sizes, int n_in,
                              void* d_out, int out_size, void* d_ws, size_t ws_size,
                              hipStream_t stream) {
  const float* x  = (const float*)d_in[0];
  const float* wg = (const float*)d_in[1];
  const float* wu = (const float*)d_in[2];
  const float* wd = (const float*)d_in[3];
  const float* wr = (const float*)d_in[4];
  float* out = (float*)d_out;
  char* ws = (char*)d_ws;
  (void)in_sizes; (void)n_in; (void)out_size; (void)ws_size;

  size_t o = 0;
  auto alloc = [&](size_t b) { size_t r = o; o += (b + 255) & ~(size_t)255; return r; };
  float* partials   = (float*)(ws + alloc(24 * 64 * 4));
  float* s_w        = (float*)(ws + alloc(24 * 4));
  float* wrq        = (float*)(ws + alloc((size_t)NEXP * HDIM * 4));
  int*   tok_e      = (int*)  (ws + alloc((size_t)T_TOK * 2 * 4));
  float* tok_g      = (float*)(ws + alloc((size_t)T_TOK * 2 * 4));
  int*   cnt        = (int*)  (ws + alloc(256));      // cnt[8] then cnt2[8]
  int*   cnt2       = cnt + 8;
  int*   offs       = (int*)  (ws + alloc(16 * 4));
  int*   tile_e     = (int*)  (ws + alloc(128 * 4));
  int*   tile_m0    = (int*)  (ws + alloc(128 * 4));
  int*   tile_cnt   = (int*)  (ws + alloc(4));
  int*   pair_tok   = (int*)  (ws + alloc((size_t)PPAD * 4));
  float* pair_gate  = (float*)(ws + alloc((size_t)PPAD * 4));
  float* pair_sx    = (float*)(ws + alloc((size_t)PPAD * 4));
  float* pair_f     = (float*)(ws + alloc((size_t)PPAD * 4));
  float* sx         = (float*)(ws + alloc((size_t)T_TOK * 4));
  signed char* xq   = (signed char*)(ws + alloc((size_t)T_TOK * HDIM));
  signed char* xqp  = (signed char*)(ws + alloc((size_t)PPAD * HDIM));
  signed char* wgp  = (signed char*)(ws + alloc((size_t)NEXP * FH));
  signed char* wup  = (signed char*)(ws + alloc((size_t)NEXP * FH));
  signed char* wdp  = (signed char*)(ws + alloc((size_t)NEXP * FH));
  unsigned short* hbuf = (unsigned short*)(ws + alloc((size_t)PPAD * FDIM * 2));
  signed char* hqp  = (signed char*)(ws + alloc((size_t)PPAD * FDIM));

  hipMemsetAsync(cnt, 0, 64, stream);
  hipMemsetAsync(pair_tok, 0, (size_t)PPAD * 4, stream);
  hipMemsetAsync(out, 0, (size_t)T_TOK * HDIM * 4, stream);

  k_wabs_partial<<<dim3(24, 64), 256, 0, stream>>>(wg, wu, wd, partials);
  k_scales<<<1, 256, 0, stream>>>(wr, partials, s_w, wrq);
  k_quant_pack<1024, 4096><<<8192, 256, 0, stream>>>(wg, wgp, s_w);
  k_quant_pack<1024, 4096><<<8192, 256, 0, stream>>>(wu, wup, s_w + 8);
  k_quant_pack<4096, 1024><<<8192, 256, 0, stream>>>(wd, wdp, s_w + 16);
  k_act_router<<<T_TOK, 256, 0, stream>>>(x, wrq, xq, sx, tok_e, tok_g, cnt);
  k_plan<<<1, 64, 0, stream>>>(cnt, offs, tile_e, tile_m0, tile_cnt);
  k_scatter<<<8, 256, 0, stream>>>(tok_e, tok_g, sx, offs, cnt2, pair_tok, pair_gate, pair_sx);
  k_packA<<<PPAD / 4, 256, 0, stream>>>(pair_tok, xq, xqp);
  k_gemm_gu<<<dim3(72, 32), 256, 0, stream>>>(xqp, wgp, wup, tile_e, tile_m0, tile_cnt,
                                              cnt, offs, pair_sx, s_w, hbuf);
  k_select<<<PPAD / 4, 256, 0, stream>>>(hbuf, hqp, pair_gate, pair_f);
  k_gemm_down<<<dim3(72, 8), 256, 0, stream>>>(hqp, wdp, tile_e, tile_m0, tile_cnt,
                                               cnt, offs, pair_tok, pair_f, s_w, out);
}

// Round 3
// 810.457 us; speedup vs baseline: 1.1877x; 1.0075x over previous
//
#include <hip/hip_runtime.h>
#include <cstdint>
#include <cstddef>

// ---------------------------------------------------------------------------
// BitMoE FFN (top-2 of 8 experts), MI355X/gfx950.  Round 3.
// Weight pipeline per tensor: wabs (coalesced, 4 indep accumulators) ->
// scales (mean + exact compare-threshold via fp-bit binary search) ->
// pack (coalesced fp32 read -> ternary int8 -> padded-LDS transpose ->
// coalesced MFMA-fragment-pack write).  Tensor stays L3-resident between
// wabs and pack.  GEMMs: int8 MFMA on fragment-packed operands.
// ---------------------------------------------------------------------------

#define T_TOK 2048
#define HDIM  1024
#define FDIM  4096
#define NEXP  8
#define FH    (FDIM * HDIM)     // 2^22
#define KTOP  2253              // ceil(0.55 * 4096)
#define EPSF  1e-8f
#define PPAD  4608              // 4096 pairs + per-expert 64-alignment padding

typedef int v4i  __attribute__((ext_vector_type(4)));
typedef int v16i __attribute__((ext_vector_type(16)));

// ---------------- pass 1: per-matrix mean|w| partials ----------------------
// grid (8, 128); block 256. Each block sums a 128KB chunk; 4 indep accums.
__global__ __launch_bounds__(256) void k_wabs(const float* __restrict__ w,
                                              float* __restrict__ partials) {
  int m = blockIdx.x, blk = blockIdx.y, tid = threadIdx.x;
  const float4* p = (const float4*)(w + (size_t)m * FH + (size_t)blk * 32768) + tid;
  float s0 = 0.f, s1 = 0.f, s2 = 0.f, s3 = 0.f;
#pragma unroll
  for (int i = 0; i < 8; i++) {
    float4 a = p[(4 * i + 0) * 256];
    float4 b = p[(4 * i + 1) * 256];
    float4 c = p[(4 * i + 2) * 256];
    float4 d = p[(4 * i + 3) * 256];
    s0 += fabsf(a.x) + fabsf(a.y) + fabsf(a.z) + fabsf(a.w);
    s1 += fabsf(b.x) + fabsf(b.y) + fabsf(b.z) + fabsf(b.w);
    s2 += fabsf(c.x) + fabsf(c.y) + fabsf(c.z) + fabsf(c.w);
    s3 += fabsf(d.x) + fabsf(d.y) + fabsf(d.z) + fabsf(d.w);
  }
  float s = (s0 + s1) + (s2 + s3);
  for (int o = 32; o > 0; o >>= 1) s += __shfl_down(s, o);
  __shared__ float lds[4];
  if ((tid & 63) == 0) lds[tid >> 6] = s;
  __syncthreads();
  if (tid == 0) partials[m * 128 + blk] = lds[0] + lds[1] + lds[2] + lds[3];
}

// -------- finalize 8 scales + exact ternary compare-thresholds -------------
// thr = largest float t with fl(t/s) <= 0.5  =>  (|w|>thr) == (rint(w/s)!=0)
__global__ __launch_bounds__(128) void k_scales8(const float* __restrict__ partials,
                                                 float* __restrict__ s8,
                                                 float* __restrict__ thr8) {
  int tid = threadIdx.x;
  __shared__ float acc[2];
  __shared__ float svals[8];
  for (int m = 0; m < 8; m++) {
    float v = partials[m * 128 + tid];
    for (int o = 32; o > 0; o >>= 1) v += __shfl_down(v, o);
    if ((tid & 63) == 0) acc[tid >> 6] = v;
    __syncthreads();
    if (tid == 0) svals[m] = fmaxf((acc[0] + acc[1]) / (float)FH, EPSF);
    __syncthreads();
  }
  if (tid < 8) {
    float s = svals[tid];
    s8[tid] = s;
    unsigned int lo = 0u, hi = __float_as_uint(s);   // fl(s/s)=1 > 0.5
    for (int it = 0; it < 32; ++it) {
      unsigned int mid = (lo + hi) >> 1;
      if (mid == lo) break;
      if (__uint_as_float(mid) / s <= 0.5f) lo = mid; else hi = mid;
    }
    thr8[tid] = __uint_as_float(lo);
  }
}

// ----------------- router int8 per-tensor quant (tiny) ---------------------
__global__ __launch_bounds__(256) void k_router(const float* __restrict__ wr,
                                                float* __restrict__ wrq) {
  int tid = threadIdx.x;
  __shared__ float lds[4];
  __shared__ float sbc;
  float mx = 0.f;
  for (int i = tid; i < NEXP * HDIM; i += 256) mx = fmaxf(mx, fabsf(wr[i]));
  for (int o = 32; o > 0; o >>= 1) mx = fmaxf(mx, __shfl_down(mx, o));
  if ((tid & 63) == 0) lds[tid >> 6] = mx;
  __syncthreads();
  if (tid == 0)
    sbc = fmaxf(fmaxf(fmaxf(lds[0], lds[1]), fmaxf(lds[2], lds[3])), EPSF) / 127.0f;
  __syncthreads();
  float s = sbc;
  for (int i = tid; i < NEXP * HDIM; i += 256) {
    float q = fminf(fmaxf(rintf(wr[i] / s), -127.f), 127.f);
    wrq[i] = q * s;
  }
}

// ------- pass 2: ternarize + transpose into MFMA fragment pack -------------
// Block owns (e, rowgrp g: 32 rows, col-slab sl: 1024 cols).
// Phase 1: coalesced fp32 read, ternary compare, int8 into padded LDS.
// Phase 2: coalesced 1KB fragment-pack writes.
template <int KD, int RD>
__global__ __launch_bounds__(256) void k_pack(const float* __restrict__ w,
                                              signed char* __restrict__ q,
                                              const float* __restrict__ thr8) {
  constexpr int GR = RD / 32, CCH = KD / 32;
  int e = blockIdx.x / GR, g = blockIdx.x % GR, sl = blockIdx.y;
  float thr = thr8[e];
  __shared__ unsigned int lds[32][257];
  int tid = threadIdx.x;
  const float* wb = w + ((size_t)e * RD + (size_t)g * 32) * KD + (size_t)sl * 1024;
#pragma unroll 4
  for (int i = 0; i < 32; i++) {
    float4 v = *(const float4*)(wb + (size_t)i * KD + tid * 4);
    unsigned int b0 = (fabsf(v.x) > thr) ? ((__float_as_uint(v.x) >> 31) ? 0xFFu : 1u) : 0u;
    unsigned int b1 = (fabsf(v.y) > thr) ? ((__float_as_uint(v.y) >> 31) ? 0xFFu : 1u) : 0u;
    unsigned int b2 = (fabsf(v.z) > thr) ? ((__float_as_uint(v.z) >> 31) ? 0xFFu : 1u) : 0u;
    unsigned int b3 = (fabsf(v.w) > thr) ? ((__float_as_uint(v.w) >> 31) ? 0xFFu : 1u) : 0u;
    lds[i][tid] = b0 | (b1 << 8) | (b2 << 16) | (b3 << 24);
  }
  __syncthreads();
  size_t obase = ((size_t)(e * GR + g) * CCH + (size_t)sl * 32) * 1024;
#pragma unroll
  for (int i2 = 0; i2 < 8; i2++) {
    int mI = i2 * 256 + tid;
    int c = mI >> 6, l2 = mI & 63, ln = l2 & 31, kh = l2 >> 5;
    uint4 d = *(const uint4*)&lds[ln][c * 8 + kh * 4];
    *(uint4*)(q + obase + (size_t)c * 1024 + (size_t)l2 * 16) = d;
  }
}

// ------------- per-token int4 act quant + router + top-2 -------------------
__global__ __launch_bounds__(256) void k_act_router(const float* __restrict__ x,
                                                    const float* __restrict__ wrq,
                                                    signed char* __restrict__ xq,
                                                    float* __restrict__ sx,
                                                    int* __restrict__ tok_e,
                                                    float* __restrict__ tok_g,
                                                    int* __restrict__ cnt) {
  int t = blockIdx.x, tid = threadIdx.x;
  float4 xv = *(const float4*)(x + (size_t)t * HDIM + tid * 4);
  __shared__ float lds[4];
  __shared__ float sbc;
  __shared__ float part[8][256];
  __shared__ float lg[8];
  float mx = fmaxf(fmaxf(fabsf(xv.x), fabsf(xv.y)), fmaxf(fabsf(xv.z), fabsf(xv.w)));
  for (int o = 32; o > 0; o >>= 1) mx = fmaxf(mx, __shfl_down(mx, o));
  if ((tid & 63) == 0) lds[tid >> 6] = mx;
  __syncthreads();
  if (tid == 0)
    sbc = fmaxf(fmaxf(fmaxf(lds[0], lds[1]), fmaxf(lds[2], lds[3])), EPSF) / 7.0f;
  __syncthreads();
  float s = sbc;
  int q0 = (int)fminf(fmaxf(rintf(xv.x / s), -7.f), 7.f);
  int q1 = (int)fminf(fmaxf(rintf(xv.y / s), -7.f), 7.f);
  int q2 = (int)fminf(fmaxf(rintf(xv.z / s), -7.f), 7.f);
  int q3 = (int)fminf(fmaxf(rintf(xv.w / s), -7.f), 7.f);
  int packed = (q0 & 255) | ((q1 & 255) << 8) | ((q2 & 255) << 16) | (q3 << 24);
  *(int*)(xq + (size_t)t * HDIM + tid * 4) = packed;
  if (tid == 0) sx[t] = s;
#pragma unroll
  for (int e = 0; e < 8; e++) {
    float4 w = *(const float4*)(wrq + e * HDIM + tid * 4);
    part[e][tid] = xv.x * w.x + xv.y * w.y + xv.z * w.z + xv.w * w.w;
  }
  __syncthreads();
  if (tid < 8) {
    float sum = 0.f;
    for (int i = 0; i < 256; i++) sum += part[tid][i];
    lg[tid] = sum;
  }
  __syncthreads();
  if (tid == 0) {
    float m = lg[0];
    for (int e = 1; e < 8; e++) m = fmaxf(m, lg[e]);
    float p[8]; float S = 0.f;
    for (int e = 0; e < 8; e++) { p[e] = expf(lg[e] - m); S += p[e]; }
    for (int e = 0; e < 8; e++) p[e] /= S;
    int e0 = 0;
    for (int e = 1; e < 8; e++) if (p[e] > p[e0]) e0 = e;
    int e1 = -1;
    for (int e = 0; e < 8; e++) { if (e == e0) continue; if (e1 < 0 || p[e] > p[e1]) e1 = e; }
    float g0 = p[e0], g1 = p[e1], gs = g0 + g1;
    tok_e[2 * t] = e0;  tok_e[2 * t + 1] = e1;
    tok_g[2 * t] = g0 / gs;  tok_g[2 * t + 1] = g1 / gs;
    atomicAdd(&cnt[e0], 1); atomicAdd(&cnt[e1], 1);
  }
}

// ------------ expert offsets (64-aligned) + tile plan ----------------------
__global__ void k_plan(const int* __restrict__ cnt, int* __restrict__ offs,
                       int* __restrict__ tile_e, int* __restrict__ tile_m0,
                       int* __restrict__ tile_cnt) {
  if (threadIdx.x == 0 && blockIdx.x == 0) {
    int o = 0;
    for (int e = 0; e < 8; e++) { offs[e] = o; o += (cnt[e] + 63) & ~63; }
    offs[8] = o;
    int tt = 0;
    for (int e = 0; e < 8; e++)
      for (int m0 = 0; m0 < cnt[e]; m0 += 64) { tile_e[tt] = e; tile_m0[tt] = m0; tt++; }
    *tile_cnt = tt;
  }
}

__global__ __launch_bounds__(256) void k_scatter(const int* __restrict__ tok_e,
                                                 const float* __restrict__ tok_g,
                                                 const float* __restrict__ sx,
                                                 const int* __restrict__ offs,
                                                 int* __restrict__ cnt2,
                                                 int* __restrict__ pair_tok,
                                                 float* __restrict__ pair_gate,
                                                 float* __restrict__ pair_sx) {
  int t = blockIdx.x * 256 + threadIdx.x;
  if (t >= T_TOK) return;
  for (int k = 0; k < 2; k++) {
    int e = tok_e[2 * t + k];
    int pos = offs[e] + atomicAdd(&cnt2[e], 1);
    pair_tok[pos] = t;
    pair_gate[pos] = tok_g[2 * t + k];
    pair_sx[pos] = sx[t];
  }
}

// ----------- gather xq rows into A-fragment pack (per pair) ----------------
__global__ __launch_bounds__(256) void k_packA(const int* __restrict__ pair_tok,
                                               const signed char* __restrict__ xq,
                                               signed char* __restrict__ xqp) {
  int idx = blockIdx.x * 256 + threadIdx.x;          // < PPAD*64
  int l = idx & 63, c = (idx >> 6) & 31, pgrp = idx >> 11;
  int p = pgrp * 32 + (l & 31);
  int tok = pair_tok[p];                             // pads memset to 0 -> safe
  const signed char* src = xq + (size_t)tok * HDIM + c * 32 + (l >> 5) * 16;
  *(int4*)(xqp + (size_t)idx * 16) = *(const int4*)src;
}

// -------- gate/up int8 MFMA GEMM + fused SiLU*u, writes h (fp16) -----------
__global__ __launch_bounds__(256) void k_gemm_gu(const signed char* __restrict__ xqp,
                                                 const signed char* __restrict__ wgp,
                                                 const signed char* __restrict__ wup,
                                                 const int* __restrict__ tile_e,
                                                 const int* __restrict__ tile_m0,
                                                 const int* __restrict__ tile_cnt,
                                                 const int* __restrict__ cnt,
                                                 const int* __restrict__ offs,
                                                 const float* __restrict__ pair_sx,
                                                 const float* __restrict__ s_w,
                                                 unsigned short* __restrict__ hbuf) {
  int bx = blockIdx.x;
  if (bx >= *tile_cnt) return;
  int e = tile_e[bx], m0 = tile_m0[bx];
  int cnt_e = cnt[e], pbase = offs[e];
  int tid = threadIdx.x;
  int wave = tid >> 6, lane = tid & 63, ln = lane & 31, kh = lane >> 5;
  int fgrp = blockIdx.y * 4 + wave;
  const signed char* bg = wgp + (((size_t)e * 128 + fgrp) * 32) * 1024 + lane * 16;
  const signed char* bu = wup + (((size_t)e * 128 + fgrp) * 32) * 1024 + lane * 16;
  const signed char* ap = xqp + ((size_t)((pbase + m0) >> 5) * 32) * 1024 + lane * 16;
  v16i accg0 = {0}, accg1 = {0}, accu0 = {0}, accu1 = {0};
#pragma unroll 8
  for (int c = 0; c < 32; c++) {
    v4i a0 = *(const v4i*)(ap + c * 1024);
    v4i a1 = *(const v4i*)(ap + 32768 + c * 1024);
    v4i b0 = *(const v4i*)(bg + c * 1024);
    v4i b1 = *(const v4i*)(bu + c * 1024);
    accg0 = __builtin_amdgcn_mfma_i32_32x32x32_i8(a0, b0, accg0, 0, 0, 0);
    accg1 = __builtin_amdgcn_mfma_i32_32x32x32_i8(a1, b0, accg1, 0, 0, 0);
    accu0 = __builtin_amdgcn_mfma_i32_32x32x32_i8(a0, b1, accu0, 0, 0, 0);
    accu1 = __builtin_amdgcn_mfma_i32_32x32x32_i8(a1, b1, accu1, 0, 0, 0);
  }
  float sg = s_w[e], su = s_w[8 + e];
  int col = blockIdx.y * 128 + wave * 32 + ln;
#pragma unroll
  for (int r = 0; r < 16; r++) {
    int rr = (r & 3) + 8 * (r >> 2) + 4 * kh;
#pragma unroll
    for (int mt = 0; mt < 2; mt++) {
      int ml = m0 + mt * 32 + rr;
      if (ml < cnt_e) {
        int p = pbase + ml;
        float sxv = pair_sx[p];
        int gi = (mt == 0) ? accg0[r] : accg1[r];
        int ui = (mt == 0) ? accu0[r] : accu1[r];
        float gf = (float)gi * (sxv * sg);
        float uf = (float)ui * (sxv * su);
        float h = gf / (1.0f + expf(-gf)) * uf;
        ((_Float16*)hbuf)[(size_t)p * FDIM + col] = (_Float16)h;
      }
    }
  }
}

// ------- per-pair exact top-k via 15-step bisection on fp16 bits -----------
__global__ __launch_bounds__(256) void k_select(const unsigned short* __restrict__ hbuf,
                                                signed char* __restrict__ hqp,
                                                const float* __restrict__ pair_gate,
                                                float* __restrict__ pair_f) {
  int wv = threadIdx.x >> 6, lane = threadIdx.x & 63;
  int p = blockIdx.x * 4 + wv;
  const unsigned short* row = hbuf + (size_t)p * FDIM + lane * 64;
  unsigned short hs[64];
#pragma unroll
  for (int i = 0; i < 8; i++)
    *(uint4*)(hs + i * 8) = *(const uint4*)(row + i * 8);
  unsigned short ua[64];
  unsigned int mxb = 0;
#pragma unroll
  for (int j = 0; j < 64; j++) {
    unsigned int u = hs[j] & 0x7fffu;
    ua[j] = (unsigned short)u;
    mxb = (u > mxb) ? u : mxb;
  }
  for (int o = 32; o > 0; o >>= 1) {
    unsigned int t = (unsigned int)__shfl_down((int)mxb, o);
    mxb = (t > mxb) ? t : mxb;
  }
  mxb = (unsigned int)__shfl((int)mxb, 0);
  unsigned int lo = 0, hi = 0x7c00u;
  for (int it = 0; it < 15; ++it) {
    unsigned int mid = (lo + hi) >> 1;
    int cnt = 0;
#pragma unroll
    for (int j = 0; j < 64; j++)
      cnt += (int)__popcll(__ballot((unsigned int)ua[j] >= mid));
    if (cnt >= KTOP) lo = mid; else hi = mid;
  }
  unsigned int thr = lo;
  unsigned short mxs = (unsigned short)mxb;
  float smax = (float)(*(const _Float16*)&mxs);
  float sq = fmaxf(smax, EPSF) / 127.0f;
  int pgrp = p >> 5, ln = p & 31;
#pragma unroll
  for (int gj = 0; gj < 4; gj++) {
    int c = 2 * lane + (gj >> 1);
    int kh = gj & 1;
    signed char outb[16];
#pragma unroll
    for (int t = 0; t < 16; t++) {
      int j = gj * 16 + t;
      float v = (float)(((const _Float16*)hs)[j]);
      float m = ((unsigned int)ua[j] >= thr) ? v : 0.0f;
      float q = fminf(fmaxf(rintf(m / sq), -127.f), 127.f);
      outb[t] = (signed char)(int)q;
    }
    *(int4*)(hqp + ((size_t)((size_t)pgrp * 128 + c) * 64 + kh * 32 + ln) * 16) =
        *(const int4*)outb;
  }
  if (lane == 0) pair_f[p] = pair_gate[p] * sq;
}

// ---------- down int8 MFMA GEMM + gated atomic combine into out ------------
__global__ __launch_bounds__(256) void k_gemm_down(const signed char* __restrict__ hqp,
                                                   const signed char* __restrict__ wdp,
                                                   const int* __restrict__ tile_e,
                                                   const int* __restrict__ tile_m0,
                                                   const int* __restrict__ tile_cnt,
                                                   const int* __restrict__ cnt,
                                                   const int* __restrict__ offs,
                                                   const int* __restrict__ pair_tok,
                                                   const float* __restrict__ pair_f,
                                                   const float* __restrict__ s_w,
                                                   float* __restrict__ out) {
  int bx = blockIdx.x;
  if (bx >= *tile_cnt) return;
  int e = tile_e[bx], m0 = tile_m0[bx];
  int cnt_e = cnt[e], pbase = offs[e];
  int tid = threadIdx.x;
  int wave = tid >> 6, lane = tid & 63, ln = lane & 31, kh = lane >> 5;
  int grp_n = blockIdx.y * 4 + wave;                  // 0..31
  const signed char* bp = wdp + (((size_t)e * 32 + grp_n) * 128) * 1024 + lane * 16;
  const signed char* ap = hqp + ((size_t)((pbase + m0) >> 5) * 128) * 1024 + lane * 16;
  v16i acc0 = {0}, acc1 = {0};
#pragma unroll 8
  for (int c = 0; c < 128; c++) {
    v4i a0 = *(const v4i*)(ap + (size_t)c * 1024);
    v4i a1 = *(const v4i*)(ap + 131072 + (size_t)c * 1024);
    v4i b  = *(const v4i*)(bp + (size_t)c * 1024);
    acc0 = __builtin_amdgcn_mfma_i32_32x32x32_i8(a0, b, acc0, 0, 0, 0);
    acc1 = __builtin_amdgcn_mfma_i32_32x32x32_i8(a1, b, acc1, 0, 0, 0);
  }
  float sd = s_w[16 + e];
  int col = blockIdx.y * 128 + wave * 32 + ln;
#pragma unroll
  for (int r = 0; r < 16; r++) {
    int rr = (r & 3) + 8 * (r >> 2) + 4 * kh;
#pragma unroll
    for (int mt = 0; mt < 2; mt++) {
      int ml = m0 + mt * 32 + rr;
      if (ml < cnt_e) {
        int p = pbase + ml;
        int ai = (mt == 0) ? acc0[r] : acc1[r];
        float v = (float)ai * (pair_f[p] * sd);
        atomicAdd(out + (size_t)pair_tok[p] * HDIM + col, v);
      }
    }
  }
}

// ---------------------------------------------------------------------------
extern "C" void kernel_launch(void* const* d_in, const int* in_sizes, int n_in,
                              void* d_out, int out_size, void* d_ws, size_t ws_size,
                              hipStream_t stream) {
  const float* x  = (const float*)d_in[0];
  const float* wg = (const float*)d_in[1];
  const float* wu = (const float*)d_in[2];
  const float* wd = (const float*)d_in[3];
  const float* wr = (const float*)d_in[4];
  float* out = (float*)d_out;
  char* ws = (char*)d_ws;
  (void)in_sizes; (void)n_in; (void)out_size; (void)ws_size;

  size_t o = 0;
  auto alloc = [&](size_t b) { size_t r = o; o += (b + 255) & ~(size_t)255; return r; };
  float* partials   = (float*)(ws + alloc(3 * 8 * 128 * 4));
  float* s_w        = (float*)(ws + alloc(24 * 4));
  float* thr_w      = (float*)(ws + alloc(24 * 4));
  float* wrq        = (float*)(ws + alloc((size_t)NEXP * HDIM * 4));
  int*   tok_e      = (int*)  (ws + alloc((size_t)T_TOK * 2 * 4));
  float* tok_g      = (float*)(ws + alloc((size_t)T_TOK * 2 * 4));
  int*   cnt        = (int*)  (ws + alloc(256));      // cnt[8] then cnt2[8]
  int*   cnt2       = cnt + 8;
  int*   offs       = (int*)  (ws + alloc(16 * 4));
  int*   tile_e     = (int*)  (ws + alloc(128 * 4));
  int*   tile_m0    = (int*)  (ws + alloc(128 * 4));
  int*   tile_cnt   = (int*)  (ws + alloc(4));
  int*   pair_tok   = (int*)  (ws + alloc((size_t)PPAD * 4));
  float* pair_gate  = (float*)(ws + alloc((size_t)PPAD * 4));
  float* pair_sx    = (float*)(ws + alloc((size_t)PPAD * 4));
  float* pair_f     = (float*)(ws + alloc((size_t)PPAD * 4));
  float* sx         = (float*)(ws + alloc((size_t)T_TOK * 4));
  signed char* xq   = (signed char*)(ws + alloc((size_t)T_TOK * HDIM));
  signed char* xqp  = (signed char*)(ws + alloc((size_t)PPAD * HDIM));
  signed char* wgp  = (signed char*)(ws + alloc((size_t)NEXP * FH));
  signed char* wup  = (signed char*)(ws + alloc((size_t)NEXP * FH));
  signed char* wdp  = (signed char*)(ws + alloc((size_t)NEXP * FH));
  unsigned short* hbuf = (unsigned short*)(ws + alloc((size_t)PPAD * FDIM * 2));
  signed char* hqp  = (signed char*)(ws + alloc((size_t)PPAD * FDIM));

  hipMemsetAsync(cnt, 0, 64, stream);
  hipMemsetAsync(pair_tok, 0, (size_t)PPAD * 4, stream);
  hipMemsetAsync(out, 0, (size_t)T_TOK * HDIM * 4, stream);

  // per-tensor: wabs -> scales -> pack (tensor stays L3-resident for pack)
  k_wabs<<<dim3(8, 128), 256, 0, stream>>>(wg, partials);
  k_scales8<<<1, 128, 0, stream>>>(partials, s_w, thr_w);
  k_pack<1024, 4096><<<dim3(1024, 1), 256, 0, stream>>>(wg, wgp, thr_w);

  k_wabs<<<dim3(8, 128), 256, 0, stream>>>(wu, partials + 1024);
  k_scales8<<<1, 128, 0, stream>>>(partials + 1024, s_w + 8, thr_w + 8);
  k_pack<1024, 4096><<<dim3(1024, 1), 256, 0, stream>>>(wu, wup, thr_w + 8);

  k_wabs<<<dim3(8, 128), 256, 0, stream>>>(wd, partials + 2048);
  k_scales8<<<1, 128, 0, stream>>>(partials + 2048, s_w + 16, thr_w + 16);
  k_pack<4096, 1024><<<dim3(256, 4), 256, 0, stream>>>(wd, wdp, thr_w + 16);

  k_router<<<1, 256, 0, stream>>>(wr, wrq);
  k_act_router<<<T_TOK, 256, 0, stream>>>(x, wrq, xq, sx, tok_e, tok_g, cnt);
  k_plan<<<1, 64, 0, stream>>>(cnt, offs, tile_e, tile_m0, tile_cnt);
  k_scatter<<<8, 256, 0, stream>>>(tok_e, tok_g, sx, offs, cnt2, pair_tok, pair_gate, pair_sx);
  k_packA<<<PPAD / 4, 256, 0, stream>>>(pair_tok, xq, xqp);
  k_gemm_gu<<<dim3(72, 32), 256, 0, stream>>>(xqp, wgp, wup, tile_e, tile_m0, tile_cnt,
                                              cnt, offs, pair_sx, s_w, hbuf);
  k_select<<<PPAD / 4, 256, 0, stream>>>(hbuf, hqp, pair_gate, pair_f);
  k_gemm_down<<<dim3(72, 8), 256, 0, stream>>>(hqp, wdp, tile_e, tile_m0, tile_cnt,
                                               cnt, offs, pair_tok, pair_f, s_w, out);
}